// Round 9
// baseline (137.675 us; speedup 1.0000x reference)
//
#include <hip/hip_runtime.h>
#include <hip/hip_bf16.h>

// Problem: B=4, L=2048, D_MODEL=1024, H=16, D_QKV=64.
// Reference einsum 'bhlk,blhd->blhd' contracts k over logits only; softmax sums to 1,
// so attention output == v and the net reduces to:
//   out = x @ Wc + fc_b,  Wc[m][j] = sum_{hd} w_v[h][m][d] * fc_w[j][hd]
// Two launches:
//   prep: blocks 0-255 fold Wc^T || blocks 256-1023 cast x->bf16 (R2-exact, best measured).
//   final_gemm: 128x64-tile GEMM, BK=32 single-buffered, 12KB LDS, 6 blocks/CU.
// History: R0 prep rewrite 151->133.5. R3 fgemm 4->3 blk/CU + dbuf: +13.4 REGRESS
//   (occupancy loss dominated). R6 counted-vmcnt: +6.2 REGRESS. R7 XCD swizzle:
//   NEUTRAL (L3-BW theory falsified). R8 fused prep: +2.4 NEUTRAL (smaller fold tiles
//   doubled redundant traffic, cancelled the TLP gain).
// Round-9: the only lever that has ever moved fgemm is blocks/CU (R3's -1 cost 13us).
//   Invert it: BK=32 single-buffer shrinks LDS 24KB->12KB; __launch_bounds__(256,6)
//   -> 6 blocks/CU (24 waves/CU, VGPR cap 85 - acc32+ptrs6+frags24 fits). Structure
//   otherwise R2-exact: stage -> sync -> compute, k-ascending accumulation (BK=32
//   numerics already validated bit-identical by R6). prep untouched from R2.

typedef __attribute__((ext_vector_type(8))) short bf16x8;
typedef __attribute__((ext_vector_type(4))) float f32x4;

__device__ __forceinline__ f32x4 mfma16(bf16x8 a, bf16x8 b, f32x4 c) {
  return __builtin_amdgcn_mfma_f32_16x16x32_bf16(a, b, c, 0, 0, 0);
}

// fp32 -> bf16 bits, round-to-nearest-even
__device__ __forceinline__ unsigned short f2b(float f) {
  unsigned int u = __builtin_bit_cast(unsigned int, f);
  return (unsigned short)((u + 0x7fffu + ((u >> 16) & 1u)) >> 16);
}

__device__ __forceinline__ bf16x8 cvt8(float4 a, float4 b) {
  bf16x8 r;
  r[0] = (short)f2b(a.x); r[1] = (short)f2b(a.y); r[2] = (short)f2b(a.z); r[3] = (short)f2b(a.w);
  r[4] = (short)f2b(b.x); r[5] = (short)f2b(b.y); r[6] = (short)f2b(b.z); r[7] = (short)f2b(b.w);
  return r;
}

// async global->LDS, 16 B per lane (m97 pattern; LDS dest = wave-uniform base + lane*16)
__device__ __forceinline__ void gld_lds16(const void* g, void* l) {
  __builtin_amdgcn_global_load_lds((const __attribute__((address_space(1))) unsigned int*)g,
                                   (__attribute__((address_space(3))) unsigned int*)l, 16, 0, 0);
}

// prep: blocks 0-255 fold Wc^T; blocks 256-1023 cast x->bf16. No inter-block dependency.
__global__ __launch_bounds__(256) void prep(const float* __restrict__ x,
                                            const float* __restrict__ wv,
                                            const float* __restrict__ fcw,
                                            unsigned short* __restrict__ xb,
                                            unsigned short* __restrict__ wcT) {
  // Fold LDS: per-h 64x64 bf16 slabs of A=fcw[j][k] and B=wv-as-[m][d], double-buffered.
  // 32 KB total. XOR swizzle (row&7)<<4 on the in-row byte so the stride-128B fragment
  // reads are <=2-way bank aliases (free) instead of 16-way.
  __shared__ __align__(16) short As[2][64 * 64];
  __shared__ __align__(16) short Bs[2][64 * 64];

  int bid = blockIdx.x, t = threadIdx.x;
  int wid = t >> 6, lane = t & 63, l16 = lane & 15, quad = lane >> 4;

  if (bid < 256) {
    // wcT[j][m] = sum_{h,d} fcw[j][h*64+d] * wv[h][m][d]; 64x64 output tile, 4 waves 2x2,
    // each wave a 32x32 sub-tile (2x2 frags of 16x16), K-loop = 16 h-slabs of 64.
    int j0 = (bid >> 4) * 64;   // j tile
    int m0 = (bid & 15) * 64;   // m tile
    int wr = wid >> 1, wc = wid & 1;
    int rowt = t >> 3, colb = (t & 7) * 8;  // staging: chunk c row = c*32+rowt, 8 floats at colb

    f32x4 acc[2][2];
#pragma unroll
    for (int a = 0; a < 2; a++)
#pragma unroll
      for (int b = 0; b < 2; b++) acc[a][b] = (f32x4){0.f, 0.f, 0.f, 0.f};

    float4 ra[2][2], rb[2][2];  // [chunk][2xfloat4] in-flight slab

#define LOADH(h)                                                                     \
    {                                                                                \
      _Pragma("unroll")                                                              \
      for (int c = 0; c < 2; c++) {                                                  \
        int row = c * 32 + rowt;                                                     \
        const float* pa = fcw + (j0 + row) * 1024 + (h) * 64 + colb;                 \
        ra[c][0] = *reinterpret_cast<const float4*>(pa);                             \
        ra[c][1] = *reinterpret_cast<const float4*>(pa + 4);                         \
        const float* pb = wv + (h) * 65536 + (m0 + row) * 64 + colb;                 \
        rb[c][0] = *reinterpret_cast<const float4*>(pb);                             \
        rb[c][1] = *reinterpret_cast<const float4*>(pb + 4);                         \
      }                                                                              \
    }
#define STOREH(buf)                                                                  \
    {                                                                                \
      _Pragma("unroll")                                                              \
      for (int c = 0; c < 2; c++) {                                                  \
        int row = c * 32 + rowt;                                                     \
        int bo = row * 128 + ((colb * 2) ^ ((row & 7) << 4));                        \
        *reinterpret_cast<bf16x8*>((char*)As[buf] + bo) = cvt8(ra[c][0], ra[c][1]);  \
        *reinterpret_cast<bf16x8*>((char*)Bs[buf] + bo) = cvt8(rb[c][0], rb[c][1]);  \
      }                                                                              \
    }

    LOADH(0);
    STOREH(0);
    __syncthreads();

    for (int h = 0; h < 16; ++h) {
      int cur = h & 1;
      if (h < 15) LOADH(h + 1);  // issue-early: HBM latency hides under frag reads + MFMA

      bf16x8 af[2][2], bg[2][2];  // [tile][ks]
#pragma unroll
      for (int rt = 0; rt < 2; rt++) {
        int rowf = wr * 32 + rt * 16 + l16;
        int rbase = rowf * 128, rx = (rowf & 7) << 4;
        af[rt][0] = *reinterpret_cast<const bf16x8*>((char*)As[cur] + rbase + ((quad * 16) ^ rx));
        af[rt][1] = *reinterpret_cast<const bf16x8*>((char*)As[cur] + rbase + ((64 + quad * 16) ^ rx));
      }
#pragma unroll
      for (int ct = 0; ct < 2; ct++) {
        int rowf = wc * 32 + ct * 16 + l16;
        int rbase = rowf * 128, rx = (rowf & 7) << 4;
        bg[ct][0] = *reinterpret_cast<const bf16x8*>((char*)Bs[cur] + rbase + ((quad * 16) ^ rx));
        bg[ct][1] = *reinterpret_cast<const bf16x8*>((char*)Bs[cur] + rbase + ((64 + quad * 16) ^ rx));
      }
#pragma unroll
      for (int ks = 0; ks < 2; ks++)
#pragma unroll
        for (int rt = 0; rt < 2; rt++)
#pragma unroll
          for (int ct = 0; ct < 2; ct++)
            acc[rt][ct] = mfma16(af[rt][ks], bg[ct][ks], acc[rt][ct]);

      if (h < 15) STOREH(cur ^ 1);  // write-late into the other buffer
      __syncthreads();
    }
#undef LOADH
#undef STOREH

#pragma unroll
    for (int rt = 0; rt < 2; rt++)
#pragma unroll
      for (int ct = 0; ct < 2; ct++) {
        int jj = j0 + wr * 32 + rt * 16 + quad * 4;
        int mm = m0 + wc * 32 + ct * 16 + l16;
#pragma unroll
        for (int r = 0; r < 4; r++) wcT[(jj + r) * 1024 + mm] = f2b(acc[rt][ct][r]);
      }
  } else {
    // cast: x fp32 -> bf16. 8.4M elems = 4096 chunks of 2048; 768 blocks grid-stride
    // (~5.3 chunks each) so HBM latency is hidden by TLP (4 blocks/CU overall grid).
    int cb = bid - 256;
    for (int ch = cb; ch < 4096; ch += 768) {
      int idx = ch * 2048 + t * 8;
      float4 a = *reinterpret_cast<const float4*>(x + idx);
      float4 b = *reinterpret_cast<const float4*>(x + idx + 4);
      *reinterpret_cast<bf16x8*>(xb + idx) = cvt8(a, b);
    }
  }
}

// out[i][j] = sum_m xb[i][m]*wcT[j][m] + fcb[j].  M=8192,N=1024,K=1024.
// 128x64 tile, BK=32, 32 K-steps, 1024 blocks N-fastest, 12KB LDS, 6 blocks/CU.
// Simple stage->sync->compute structure (all pipelining attempts R3/R6 regressed);
// occupancy is the lever: 6 blocks/CU = 24 waves/CU of uncorrelated stall phases.
__global__ __launch_bounds__(256, 6) void final_gemm(const unsigned short* __restrict__ xb,
                                                     const unsigned short* __restrict__ wcT,
                                                     const float* __restrict__ fcb,
                                                     float* __restrict__ out) {
  __shared__ __align__(16) unsigned short As[128 * 32];  // 8 KB
  __shared__ __align__(16) unsigned short Bs[64 * 32];   // 4 KB
  int t = threadIdx.x, wid = t >> 6, lane = t & 63, l16 = lane & 15, quad = lane >> 4;
  int wr = wid >> 1, wc = wid & 1;
  int row0 = (blockIdx.x >> 4) * 128;   // M tile (64)
  int col0 = (blockIdx.x & 15) * 64;    // N tile (16) — fastest: B stays L2-hot

  // A: 128x32 = 8 chunks of 1KB (16 rows each); wave wid stages chunks wid*2, wid*2+1.
  // B: 64x32 = 4 chunks; wave wid stages chunk wid.
  // Within a chunk: lane l -> row (l>>2), k-quarter (l&3)*8 elems. LDS dest linear lane*16B.
  const unsigned short* Ap[2];
  const unsigned short* Bp;
#pragma unroll
  for (int j = 0; j < 2; j++) {
    int blk = wid * 2 + j;
    int row = blk * 16 + (lane >> 2), kq = lane & 3;
    Ap[j] = xb + (row0 + row) * 1024 + kq * 8;
  }
  {
    int row = wid * 16 + (lane >> 2), kq = lane & 3;
    Bp = wcT + (col0 + row) * 1024 + kq * 8;
  }

  f32x4 acc[4][2];
#pragma unroll
  for (int rt = 0; rt < 4; rt++)
#pragma unroll
    for (int ct = 0; ct < 2; ct++) acc[rt][ct] = (f32x4){0.f, 0.f, 0.f, 0.f};

  for (int k0 = 0; k0 < 1024; k0 += 32) {
    __syncthreads();  // close WAR: everyone done reading LDS from previous step
#pragma unroll
    for (int j = 0; j < 2; j++) gld_lds16(Ap[j] + k0, &As[(wid * 2 + j) * 512 + lane * 8]);
    gld_lds16(Bp + k0, &Bs[wid * 512 + lane * 8]);
    __syncthreads();  // implied vmcnt(0): tile present for all waves
    bf16x8 af[4], bfr[2];
#pragma unroll
    for (int rt = 0; rt < 4; rt++)
      af[rt] = *reinterpret_cast<const bf16x8*>(&As[(wr * 64 + rt * 16 + l16) * 32 + quad * 8]);
#pragma unroll
    for (int ct = 0; ct < 2; ct++)
      bfr[ct] = *reinterpret_cast<const bf16x8*>(&Bs[(wc * 32 + ct * 16 + l16) * 32 + quad * 8]);
#pragma unroll
    for (int rt = 0; rt < 4; rt++)
#pragma unroll
      for (int ct = 0; ct < 2; ct++)
        acc[rt][ct] = mfma16(af[rt], bfr[ct], acc[rt][ct]);
  }

#pragma unroll
  for (int ct = 0; ct < 2; ct++) {
    int j = col0 + wc * 32 + ct * 16 + l16;
    float bias = fcb[j];
#pragma unroll
    for (int rt = 0; rt < 4; rt++) {
      int i0 = row0 + wr * 64 + rt * 16 + quad * 4;
      f32x4 a = acc[rt][ct];
#pragma unroll
      for (int r = 0; r < 4; r++) out[(i0 + r) * 1024 + j] = a[r] + bias;
    }
  }
}

extern "C" void kernel_launch(void* const* d_in, const int* in_sizes, int n_in,
                              void* d_out, int out_size, void* d_ws, size_t ws_size,
                              hipStream_t stream) {
  const float* x   = (const float*)d_in[0];
  // d_in[1] mask, d_in[2] w_q, d_in[3] w_k: dead per reference semantics
  const float* wv  = (const float*)d_in[4];
  const float* fcw = (const float*)d_in[5];
  const float* fcb = (const float*)d_in[6];
  float* out = (float*)d_out;

  char* ws = (char*)d_ws;
  unsigned short* xb  = (unsigned short*)(ws);              // 16 MB (8192x1024 bf16)
  unsigned short* wcT = (unsigned short*)(ws + 16777216);   // 2 MB  (1024x1024 bf16)

  prep<<<1024, 256, 0, stream>>>(x, wv, fcw, xb, wcT);
  final_gemm<<<1024, 256, 0, stream>>>(xb, wcT, fcb, out);
}

// Round 10
// 131.085 us; speedup vs baseline: 1.0503x; 1.0503x over previous
//
#include <hip/hip_runtime.h>
#include <hip/hip_bf16.h>

// Problem: B=4, L=2048, D_MODEL=1024, H=16, D_QKV=64.
// Reference einsum 'bhlk,blhd->blhd' contracts k over logits only; softmax sums to 1,
// so attention output == v and the net reduces to:
//   out = x @ Wc + fc_b,  Wc[m][j] = sum_{hd} w_v[h][m][d] * fc_w[j][hd]
// Two launches:
//   prep: blocks 0-255 fold Wc^T || blocks 256-1023 cast x->bf16 (R2-exact, best measured).
//   final_gemm: m97-geometry 128x128 tile, BK=64, 4 waves, 4x4 acc/wave, 512 blocks.
// History: R0 prep rewrite 151->133.5 (best). fgemm attacks: R3 dbuf+3blk/CU -13.4;
//   R6 counted-vmcnt -6.2; R7 XCD swizzle 0; R9 6blk/CU BK=32 -4.2. All scheduling/
//   locality/occupancy axes exhausted — NONE touched arithmetic intensity.
// Round-10: port the guide's verified m93->m97 geometry (the 517->874 TF step): 128x128
//   tile, BK=64, same 2-barrier stage->sync->compute structure. Per wave-K-step: 32 MFMA
//   vs 8 staged loads (2x current ratio). Staged traffic 384->256MB; barrier-steps 4x
//   fewer. Bit-identical output (same 32-step k-ascending mfma chain per element).

typedef __attribute__((ext_vector_type(8))) short bf16x8;
typedef __attribute__((ext_vector_type(4))) float f32x4;

__device__ __forceinline__ f32x4 mfma16(bf16x8 a, bf16x8 b, f32x4 c) {
  return __builtin_amdgcn_mfma_f32_16x16x32_bf16(a, b, c, 0, 0, 0);
}

// fp32 -> bf16 bits, round-to-nearest-even
__device__ __forceinline__ unsigned short f2b(float f) {
  unsigned int u = __builtin_bit_cast(unsigned int, f);
  return (unsigned short)((u + 0x7fffu + ((u >> 16) & 1u)) >> 16);
}

__device__ __forceinline__ bf16x8 cvt8(float4 a, float4 b) {
  bf16x8 r;
  r[0] = (short)f2b(a.x); r[1] = (short)f2b(a.y); r[2] = (short)f2b(a.z); r[3] = (short)f2b(a.w);
  r[4] = (short)f2b(b.x); r[5] = (short)f2b(b.y); r[6] = (short)f2b(b.z); r[7] = (short)f2b(b.w);
  return r;
}

// async global->LDS, 16 B per lane (m97 pattern; LDS dest = wave-uniform base + lane*16)
__device__ __forceinline__ void gld_lds16(const void* g, void* l) {
  __builtin_amdgcn_global_load_lds((const __attribute__((address_space(1))) unsigned int*)g,
                                   (__attribute__((address_space(3))) unsigned int*)l, 16, 0, 0);
}

// prep: blocks 0-255 fold Wc^T; blocks 256-1023 cast x->bf16. No inter-block dependency.
__global__ __launch_bounds__(256) void prep(const float* __restrict__ x,
                                            const float* __restrict__ wv,
                                            const float* __restrict__ fcw,
                                            unsigned short* __restrict__ xb,
                                            unsigned short* __restrict__ wcT) {
  // Fold LDS: per-h 64x64 bf16 slabs of A=fcw[j][k] and B=wv-as-[m][d], double-buffered.
  // 32 KB total. XOR swizzle (row&7)<<4 on the in-row byte so the stride-128B fragment
  // reads are <=2-way bank aliases (free) instead of 16-way.
  __shared__ __align__(16) short As[2][64 * 64];
  __shared__ __align__(16) short Bs[2][64 * 64];

  int bid = blockIdx.x, t = threadIdx.x;
  int wid = t >> 6, lane = t & 63, l16 = lane & 15, quad = lane >> 4;

  if (bid < 256) {
    // wcT[j][m] = sum_{h,d} fcw[j][h*64+d] * wv[h][m][d]; 64x64 output tile, 4 waves 2x2,
    // each wave a 32x32 sub-tile (2x2 frags of 16x16), K-loop = 16 h-slabs of 64.
    int j0 = (bid >> 4) * 64;   // j tile
    int m0 = (bid & 15) * 64;   // m tile
    int wr = wid >> 1, wc = wid & 1;
    int rowt = t >> 3, colb = (t & 7) * 8;  // staging: chunk c row = c*32+rowt, 8 floats at colb

    f32x4 acc[2][2];
#pragma unroll
    for (int a = 0; a < 2; a++)
#pragma unroll
      for (int b = 0; b < 2; b++) acc[a][b] = (f32x4){0.f, 0.f, 0.f, 0.f};

    float4 ra[2][2], rb[2][2];  // [chunk][2xfloat4] in-flight slab

#define LOADH(h)                                                                     \
    {                                                                                \
      _Pragma("unroll")                                                              \
      for (int c = 0; c < 2; c++) {                                                  \
        int row = c * 32 + rowt;                                                     \
        const float* pa = fcw + (j0 + row) * 1024 + (h) * 64 + colb;                 \
        ra[c][0] = *reinterpret_cast<const float4*>(pa);                             \
        ra[c][1] = *reinterpret_cast<const float4*>(pa + 4);                         \
        const float* pb = wv + (h) * 65536 + (m0 + row) * 64 + colb;                 \
        rb[c][0] = *reinterpret_cast<const float4*>(pb);                             \
        rb[c][1] = *reinterpret_cast<const float4*>(pb + 4);                         \
      }                                                                              \
    }
#define STOREH(buf)                                                                  \
    {                                                                                \
      _Pragma("unroll")                                                              \
      for (int c = 0; c < 2; c++) {                                                  \
        int row = c * 32 + rowt;                                                     \
        int bo = row * 128 + ((colb * 2) ^ ((row & 7) << 4));                        \
        *reinterpret_cast<bf16x8*>((char*)As[buf] + bo) = cvt8(ra[c][0], ra[c][1]);  \
        *reinterpret_cast<bf16x8*>((char*)Bs[buf] + bo) = cvt8(rb[c][0], rb[c][1]);  \
      }                                                                              \
    }

    LOADH(0);
    STOREH(0);
    __syncthreads();

    for (int h = 0; h < 16; ++h) {
      int cur = h & 1;
      if (h < 15) LOADH(h + 1);  // issue-early: HBM latency hides under frag reads + MFMA

      bf16x8 af[2][2], bg[2][2];  // [tile][ks]
#pragma unroll
      for (int rt = 0; rt < 2; rt++) {
        int rowf = wr * 32 + rt * 16 + l16;
        int rbase = rowf * 128, rx = (rowf & 7) << 4;
        af[rt][0] = *reinterpret_cast<const bf16x8*>((char*)As[cur] + rbase + ((quad * 16) ^ rx));
        af[rt][1] = *reinterpret_cast<const bf16x8*>((char*)As[cur] + rbase + ((64 + quad * 16) ^ rx));
      }
#pragma unroll
      for (int ct = 0; ct < 2; ct++) {
        int rowf = wc * 32 + ct * 16 + l16;
        int rbase = rowf * 128, rx = (rowf & 7) << 4;
        bg[ct][0] = *reinterpret_cast<const bf16x8*>((char*)Bs[cur] + rbase + ((quad * 16) ^ rx));
        bg[ct][1] = *reinterpret_cast<const bf16x8*>((char*)Bs[cur] + rbase + ((64 + quad * 16) ^ rx));
      }
#pragma unroll
      for (int ks = 0; ks < 2; ks++)
#pragma unroll
        for (int rt = 0; rt < 2; rt++)
#pragma unroll
          for (int ct = 0; ct < 2; ct++)
            acc[rt][ct] = mfma16(af[rt][ks], bg[ct][ks], acc[rt][ct]);

      if (h < 15) STOREH(cur ^ 1);  // write-late into the other buffer
      __syncthreads();
    }
#undef LOADH
#undef STOREH

#pragma unroll
    for (int rt = 0; rt < 2; rt++)
#pragma unroll
      for (int ct = 0; ct < 2; ct++) {
        int jj = j0 + wr * 32 + rt * 16 + quad * 4;
        int mm = m0 + wc * 32 + ct * 16 + l16;
#pragma unroll
        for (int r = 0; r < 4; r++) wcT[(jj + r) * 1024 + mm] = f2b(acc[rt][ct][r]);
      }
  } else {
    // cast: x fp32 -> bf16. 8.4M elems = 4096 chunks of 2048; 768 blocks grid-stride
    // (~5.3 chunks each) so HBM latency is hidden by TLP (4 blocks/CU overall grid).
    int cb = bid - 256;
    for (int ch = cb; ch < 4096; ch += 768) {
      int idx = ch * 2048 + t * 8;
      float4 a = *reinterpret_cast<const float4*>(x + idx);
      float4 b = *reinterpret_cast<const float4*>(x + idx + 4);
      *reinterpret_cast<bf16x8*>(xb + idx) = cvt8(a, b);
    }
  }
}

// out[i][j] = sum_m xb[i][m]*wcT[j][m] + fcb[j].  M=8192,N=1024,K=1024.
// m97 geometry: 128x128 tile, BK=64 (two 32-k slabs), 512 blocks (64 M x 8 N, N-fastest),
// 4 waves each owning a 64x64 sub-tile (4x4 frags), 32 KB LDS, 2-barrier K-step.
// Per wave-K-step: 32 MFMA vs 8 staged loads — 2x the intensity of the 128x64 tile.
__global__ __launch_bounds__(256, 2) void final_gemm(const unsigned short* __restrict__ xb,
                                                     const unsigned short* __restrict__ wcT,
                                                     const float* __restrict__ fcb,
                                                     float* __restrict__ out) {
  __shared__ __align__(16) unsigned short As[2 * 128 * 32];  // 16 KB  [slab][row][32]
  __shared__ __align__(16) unsigned short Bs[2 * 128 * 32];  // 16 KB  [slab][row][32]
  int t = threadIdx.x, wid = t >> 6, lane = t & 63, l16 = lane & 15, quad = lane >> 4;
  int wr = wid >> 1, wc = wid & 1;
  int row0 = (blockIdx.x >> 3) * 128;   // M tile (64)
  int col0 = (blockIdx.x & 7) * 128;    // N tile (8) — fastest: B stays L2-hot

  // A and B staging: 16 x 1KB chunks each; blk = wid*4+j: slab blk>>3,
  // rows (blk&7)*16 + lane>>2, kq lane&3. LDS dest linear: chunk blk at blk*1KB, lane*16B.
  int w4 = wid * 4;
  const unsigned short* Ap[4];
  const unsigned short* Bp[4];
#pragma unroll
  for (int j = 0; j < 4; j++) {
    int blk = w4 + j, s = blk >> 3;
    int row = (blk & 7) * 16 + (lane >> 2), kq = lane & 3;
    Ap[j] = xb + (row0 + row) * 1024 + s * 32 + kq * 8;
    Bp[j] = wcT + (col0 + row) * 1024 + s * 32 + kq * 8;
  }

  f32x4 acc[4][4];
#pragma unroll
  for (int rt = 0; rt < 4; rt++)
#pragma unroll
    for (int ct = 0; ct < 4; ct++) acc[rt][ct] = (f32x4){0.f, 0.f, 0.f, 0.f};

  for (int k0 = 0; k0 < 1024; k0 += 64) {
    __syncthreads();
#pragma unroll
    for (int j = 0; j < 4; j++) {
      gld_lds16(Ap[j] + k0, &As[(w4 + j) * 512 + lane * 8]);
      gld_lds16(Bp[j] + k0, &Bs[(w4 + j) * 512 + lane * 8]);
    }
    __syncthreads();
#pragma unroll
    for (int s = 0; s < 2; s++) {
      bf16x8 af[4], bfr[4];
#pragma unroll
      for (int rt = 0; rt < 4; rt++)
        af[rt] = *reinterpret_cast<const bf16x8*>(&As[s * 4096 + (wr * 64 + rt * 16 + l16) * 32 + quad * 8]);
#pragma unroll
      for (int ct = 0; ct < 4; ct++)
        bfr[ct] = *reinterpret_cast<const bf16x8*>(&Bs[s * 4096 + (wc * 64 + ct * 16 + l16) * 32 + quad * 8]);
#pragma unroll
      for (int rt = 0; rt < 4; rt++)
#pragma unroll
        for (int ct = 0; ct < 4; ct++)
          acc[rt][ct] = mfma16(af[rt], bfr[ct], acc[rt][ct]);
    }
  }

#pragma unroll
  for (int ct = 0; ct < 4; ct++) {
    int j = col0 + wc * 64 + ct * 16 + l16;
    float bias = fcb[j];
#pragma unroll
    for (int rt = 0; rt < 4; rt++) {
      int i0 = row0 + wr * 64 + rt * 16 + quad * 4;
      f32x4 a = acc[rt][ct];
#pragma unroll
      for (int r = 0; r < 4; r++) out[(i0 + r) * 1024 + j] = a[r] + bias;
    }
  }
}

extern "C" void kernel_launch(void* const* d_in, const int* in_sizes, int n_in,
                              void* d_out, int out_size, void* d_ws, size_t ws_size,
                              hipStream_t stream) {
  const float* x   = (const float*)d_in[0];
  // d_in[1] mask, d_in[2] w_q, d_in[3] w_k: dead per reference semantics
  const float* wv  = (const float*)d_in[4];
  const float* fcw = (const float*)d_in[5];
  const float* fcb = (const float*)d_in[6];
  float* out = (float*)d_out;

  char* ws = (char*)d_ws;
  unsigned short* xb  = (unsigned short*)(ws);              // 16 MB (8192x1024 bf16)
  unsigned short* wcT = (unsigned short*)(ws + 16777216);   // 2 MB  (1024x1024 bf16)

  prep<<<1024, 256, 0, stream>>>(x, wv, fcw, xb, wcT);
  final_gemm<<<512, 256, 0, stream>>>(xb, wcT, fcb, out);
}

// Round 11
// 127.240 us; speedup vs baseline: 1.0820x; 1.0302x over previous
//
#include <hip/hip_runtime.h>
#include <hip/hip_bf16.h>

// Problem: B=4, L=2048, D_MODEL=1024, H=16, D_QKV=64.
// Reference einsum 'bhlk,blhd->blhd' contracts k over logits only; softmax sums to 1,
// so attention output == v and the net reduces to:
//   out = x @ Wc + fc_b,  Wc[m][j] = sum_{hd} w_v[h][m][d] * fc_w[j][hd]
// Two launches:
//   prep: blocks 0-255 fold Wc^T || blocks 256-1023 cast x->bf16.
//   final_gemm: m97-geometry 128x128, BK=64, 512 blocks, 2/CU (R10: 131.1, best).
// History: R0 prep rewrite 151->133.5. fgemm: R3 dbuf -13.4; R6 vmcnt -6.2; R7 swizzle
//   0; R9 6blk/CU -4.2; R10 128x128 intensity +2.4 WIN (131.1).
// Round-11 (two orthogonal low-risk changes):
//   (a) prep fold: distance-2 register prefetch. Fold is a tiny 1024^3 GEMM (guide
//       shape curve: N=1024 -> 90 TF, latency-dominated). Distance-1 gave loads only
//       ~250cy of flight vs ~600-900cy L3 latency -> ~400cy stall x 16 iters. Two reg
//       sets, loop unrolled x2 (static reg indices, rule #20), LOADH(h+2) issued ~1.5
//       iters early. Compiler-managed reg deps; barriers/LDS/accum order UNCHANGED.
//   (b) fgemm: chunked bijective swizzle (512 = 8 XCD x 64): XCD owns 8M x 8N ->
//       2MB A + 2MB B = L2-fit (L3->L2 traffic 130 -> 32 MB). Mapping-only.

typedef __attribute__((ext_vector_type(8))) short bf16x8;
typedef __attribute__((ext_vector_type(4))) float f32x4;

__device__ __forceinline__ f32x4 mfma16(bf16x8 a, bf16x8 b, f32x4 c) {
  return __builtin_amdgcn_mfma_f32_16x16x32_bf16(a, b, c, 0, 0, 0);
}

// fp32 -> bf16 bits, round-to-nearest-even
__device__ __forceinline__ unsigned short f2b(float f) {
  unsigned int u = __builtin_bit_cast(unsigned int, f);
  return (unsigned short)((u + 0x7fffu + ((u >> 16) & 1u)) >> 16);
}

__device__ __forceinline__ bf16x8 cvt8(float4 a, float4 b) {
  bf16x8 r;
  r[0] = (short)f2b(a.x); r[1] = (short)f2b(a.y); r[2] = (short)f2b(a.z); r[3] = (short)f2b(a.w);
  r[4] = (short)f2b(b.x); r[5] = (short)f2b(b.y); r[6] = (short)f2b(b.z); r[7] = (short)f2b(b.w);
  return r;
}

// async global->LDS, 16 B per lane (m97 pattern; LDS dest = wave-uniform base + lane*16)
__device__ __forceinline__ void gld_lds16(const void* g, void* l) {
  __builtin_amdgcn_global_load_lds((const __attribute__((address_space(1))) unsigned int*)g,
                                   (__attribute__((address_space(3))) unsigned int*)l, 16, 0, 0);
}

// prep: blocks 0-255 fold Wc^T; blocks 256-1023 cast x->bf16. No inter-block dependency.
__global__ __launch_bounds__(256) void prep(const float* __restrict__ x,
                                            const float* __restrict__ wv,
                                            const float* __restrict__ fcw,
                                            unsigned short* __restrict__ xb,
                                            unsigned short* __restrict__ wcT) {
  // Fold LDS: per-h 64x64 bf16 slabs of A=fcw[j][k] and B=wv-as-[m][d], double-buffered.
  // 32 KB total. XOR swizzle (row&7)<<4 on the in-row byte so the stride-128B fragment
  // reads are <=2-way bank aliases (free) instead of 16-way.
  __shared__ __align__(16) short As[2][64 * 64];
  __shared__ __align__(16) short Bs[2][64 * 64];

  int bid = blockIdx.x, t = threadIdx.x;
  int wid = t >> 6, lane = t & 63, l16 = lane & 15, quad = lane >> 4;

  if (bid < 256) {
    // wcT[j][m] = sum_{h,d} fcw[j][h*64+d] * wv[h][m][d]; 64x64 output tile, 4 waves 2x2,
    // each wave a 32x32 sub-tile (2x2 frags of 16x16), K-loop = 16 h-slabs of 64.
    int j0 = (bid >> 4) * 64;   // j tile
    int m0 = (bid & 15) * 64;   // m tile
    int wr = wid >> 1, wc = wid & 1;
    int rowt = t >> 3, colb = (t & 7) * 8;  // staging: chunk c row = c*32+rowt, 8 floats at colb

    f32x4 acc[2][2];
#pragma unroll
    for (int a = 0; a < 2; a++)
#pragma unroll
      for (int b = 0; b < 2; b++) acc[a][b] = (f32x4){0.f, 0.f, 0.f, 0.f};

    // two in-flight h-slab register sets (distance-2 prefetch; static names per rule #20)
    float4 ra0[2][2], rb0[2][2], ra1[2][2], rb1[2][2];

#define LOADH(h, ra, rb)                                                             \
    {                                                                                \
      _Pragma("unroll")                                                              \
      for (int c = 0; c < 2; c++) {                                                  \
        int row = c * 32 + rowt;                                                     \
        const float* pa = fcw + (j0 + row) * 1024 + (h) * 64 + colb;                 \
        ra[c][0] = *reinterpret_cast<const float4*>(pa);                             \
        ra[c][1] = *reinterpret_cast<const float4*>(pa + 4);                         \
        const float* pb = wv + (h) * 65536 + (m0 + row) * 64 + colb;                 \
        rb[c][0] = *reinterpret_cast<const float4*>(pb);                             \
        rb[c][1] = *reinterpret_cast<const float4*>(pb + 4);                         \
      }                                                                              \
    }
#define STOREH(buf, ra, rb)                                                          \
    {                                                                                \
      _Pragma("unroll")                                                              \
      for (int c = 0; c < 2; c++) {                                                  \
        int row = c * 32 + rowt;                                                     \
        int bo = row * 128 + ((colb * 2) ^ ((row & 7) << 4));                        \
        *reinterpret_cast<bf16x8*>((char*)As[buf] + bo) = cvt8(ra[c][0], ra[c][1]);  \
        *reinterpret_cast<bf16x8*>((char*)Bs[buf] + bo) = cvt8(rb[c][0], rb[c][1]);  \
      }                                                                              \
    }
#define COMPUTE_FOLD(buf)                                                            \
    {                                                                                \
      bf16x8 af[2][2], bg[2][2];                                                     \
      _Pragma("unroll")                                                              \
      for (int rt = 0; rt < 2; rt++) {                                               \
        int rowf = wr * 32 + rt * 16 + l16;                                          \
        int rbase = rowf * 128, rx = (rowf & 7) << 4;                                \
        af[rt][0] = *reinterpret_cast<const bf16x8*>((char*)As[buf] + rbase + ((quad * 16) ^ rx));        \
        af[rt][1] = *reinterpret_cast<const bf16x8*>((char*)As[buf] + rbase + ((64 + quad * 16) ^ rx));   \
      }                                                                              \
      _Pragma("unroll")                                                              \
      for (int ct = 0; ct < 2; ct++) {                                               \
        int rowf = wc * 32 + ct * 16 + l16;                                          \
        int rbase = rowf * 128, rx = (rowf & 7) << 4;                                \
        bg[ct][0] = *reinterpret_cast<const bf16x8*>((char*)Bs[buf] + rbase + ((quad * 16) ^ rx));        \
        bg[ct][1] = *reinterpret_cast<const bf16x8*>((char*)Bs[buf] + rbase + ((64 + quad * 16) ^ rx));   \
      }                                                                              \
      _Pragma("unroll")                                                              \
      for (int ks = 0; ks < 2; ks++)                                                 \
        _Pragma("unroll")                                                            \
        for (int rt = 0; rt < 2; rt++)                                               \
          _Pragma("unroll")                                                          \
          for (int ct = 0; ct < 2; ct++)                                             \
            acc[rt][ct] = mfma16(af[rt][ks], bg[ct][ks], acc[rt][ct]);               \
    }

    // prologue: h0 and h1 both in flight; h0 staged to buf0
    LOADH(0, ra0, rb0);
    LOADH(1, ra1, rb1);
    STOREH(0, ra0, rb0);
    __syncthreads();

    // unrolled x2: iter h=hh (buf0) then h=hh+1 (buf1). Same h/ks-ascending MFMA
    // chain as before -> bit-identical. LOADH(h+2) issued ~1.5 iters before its STOREH.
    for (int hh = 0; hh < 16; hh += 2) {
      if (hh < 14) LOADH(hh + 2, ra0, rb0);
      COMPUTE_FOLD(0);
      STOREH(1, ra1, rb1);            // h = hh+1 data -> buf1 (hh+1 <= 15 always)
      __syncthreads();

      if (hh < 13) LOADH(hh + 3, ra1, rb1);
      COMPUTE_FOLD(1);
      if (hh < 14) STOREH(0, ra0, rb0);  // h = hh+2 data -> buf0
      __syncthreads();
    }
#undef LOADH
#undef STOREH
#undef COMPUTE_FOLD

#pragma unroll
    for (int rt = 0; rt < 2; rt++)
#pragma unroll
      for (int ct = 0; ct < 2; ct++) {
        int jj = j0 + wr * 32 + rt * 16 + quad * 4;
        int mm = m0 + wc * 32 + ct * 16 + l16;
#pragma unroll
        for (int r = 0; r < 4; r++) wcT[(jj + r) * 1024 + mm] = f2b(acc[rt][ct][r]);
      }
  } else {
    // cast: x fp32 -> bf16. 8.4M elems = 4096 chunks of 2048; 768 blocks grid-stride
    // (~5.3 chunks each) so HBM latency is hidden by TLP (4 blocks/CU overall grid).
    int cb = bid - 256;
    for (int ch = cb; ch < 4096; ch += 768) {
      int idx = ch * 2048 + t * 8;
      float4 a = *reinterpret_cast<const float4*>(x + idx);
      float4 b = *reinterpret_cast<const float4*>(x + idx + 4);
      *reinterpret_cast<bf16x8*>(xb + idx) = cvt8(a, b);
    }
  }
}

// out[i][j] = sum_m xb[i][m]*wcT[j][m] + fcb[j].  M=8192,N=1024,K=1024.
// m97 geometry: 128x128 tile, BK=64 (two 32-k slabs), 512 blocks, 4 waves each owning
// a 64x64 sub-tile (4x4 frags), 32 KB LDS, 2-barrier K-step, 2 blocks/CU.
// Chunked bijective swizzle (512 = 8 XCD x 64): XCD owns 8 M x 8 N consecutive tiles
// -> per-XCD L2 working set 2MB A + 2MB B (fits 4MB); L3->L2 traffic 130 -> 32 MB.
__global__ __launch_bounds__(256, 2) void final_gemm(const unsigned short* __restrict__ xb,
                                                     const unsigned short* __restrict__ wcT,
                                                     const float* __restrict__ fcb,
                                                     float* __restrict__ out) {
  __shared__ __align__(16) unsigned short As[2 * 128 * 32];  // 16 KB  [slab][row][32]
  __shared__ __align__(16) unsigned short Bs[2 * 128 * 32];  // 16 KB  [slab][row][32]
  int t = threadIdx.x, wid = t >> 6, lane = t & 63, l16 = lane & 15, quad = lane >> 4;
  int wr = wid >> 1, wc = wid & 1;
  int swz = (blockIdx.x & 7) * 64 + (blockIdx.x >> 3);  // bijective: 512 = 8 x 64
  int row0 = (swz >> 3) * 128;   // M tile (64)
  int col0 = (swz & 7) * 128;    // N tile (8) — fastest within an XCD chunk

  // A and B staging: 16 x 1KB chunks each; blk = wid*4+j: slab blk>>3,
  // rows (blk&7)*16 + lane>>2, kq lane&3. LDS dest linear: chunk blk at blk*1KB, lane*16B.
  int w4 = wid * 4;
  const unsigned short* Ap[4];
  const unsigned short* Bp[4];
#pragma unroll
  for (int j = 0; j < 4; j++) {
    int blk = w4 + j, s = blk >> 3;
    int row = (blk & 7) * 16 + (lane >> 2), kq = lane & 3;
    Ap[j] = xb + (row0 + row) * 1024 + s * 32 + kq * 8;
    Bp[j] = wcT + (col0 + row) * 1024 + s * 32 + kq * 8;
  }

  f32x4 acc[4][4];
#pragma unroll
  for (int rt = 0; rt < 4; rt++)
#pragma unroll
    for (int ct = 0; ct < 4; ct++) acc[rt][ct] = (f32x4){0.f, 0.f, 0.f, 0.f};

  for (int k0 = 0; k0 < 1024; k0 += 64) {
    __syncthreads();
#pragma unroll
    for (int j = 0; j < 4; j++) {
      gld_lds16(Ap[j] + k0, &As[(w4 + j) * 512 + lane * 8]);
      gld_lds16(Bp[j] + k0, &Bs[(w4 + j) * 512 + lane * 8]);
    }
    __syncthreads();
#pragma unroll
    for (int s = 0; s < 2; s++) {
      bf16x8 af[4], bfr[4];
#pragma unroll
      for (int rt = 0; rt < 4; rt++)
        af[rt] = *reinterpret_cast<const bf16x8*>(&As[s * 4096 + (wr * 64 + rt * 16 + l16) * 32 + quad * 8]);
#pragma unroll
      for (int ct = 0; ct < 4; ct++)
        bfr[ct] = *reinterpret_cast<const bf16x8*>(&Bs[s * 4096 + (wc * 64 + ct * 16 + l16) * 32 + quad * 8]);
#pragma unroll
      for (int rt = 0; rt < 4; rt++)
#pragma unroll
        for (int ct = 0; ct < 4; ct++)
          acc[rt][ct] = mfma16(af[rt], bfr[ct], acc[rt][ct]);
    }
  }

#pragma unroll
  for (int ct = 0; ct < 4; ct++) {
    int j = col0 + wc * 64 + ct * 16 + l16;
    float bias = fcb[j];
#pragma unroll
    for (int rt = 0; rt < 4; rt++) {
      int i0 = row0 + wr * 64 + rt * 16 + quad * 4;
      f32x4 a = acc[rt][ct];
#pragma unroll
      for (int r = 0; r < 4; r++) out[(i0 + r) * 1024 + j] = a[r] + bias;
    }
  }
}

extern "C" void kernel_launch(void* const* d_in, const int* in_sizes, int n_in,
                              void* d_out, int out_size, void* d_ws, size_t ws_size,
                              hipStream_t stream) {
  const float* x   = (const float*)d_in[0];
  // d_in[1] mask, d_in[2] w_q, d_in[3] w_k: dead per reference semantics
  const float* wv  = (const float*)d_in[4];
  const float* fcw = (const float*)d_in[5];
  const float* fcb = (const float*)d_in[6];
  float* out = (float*)d_out;

  char* ws = (char*)d_ws;
  unsigned short* xb  = (unsigned short*)(ws);              // 16 MB (8192x1024 bf16)
  unsigned short* wcT = (unsigned short*)(ws + 16777216);   // 2 MB  (1024x1024 bf16)

  prep<<<1024, 256, 0, stream>>>(x, wv, fcw, xb, wcT);
  final_gemm<<<512, 256, 0, stream>>>(xb, wcT, fcb, out);
}